// Round 1
// baseline (854.439 us; speedup 1.0000x reference)
//
#include <hip/hip_runtime.h>
#include <stdint.h>

#define S_DIM 8192
#define IN_DIM 4096
#define OUT_DIM 4096
#define R_DIM 16
#define NUM_A 8
#define SCALING 0.5f

typedef __attribute__((ext_vector_type(4))) float f32x4;
typedef __attribute__((ext_vector_type(8))) __bf16 bf16x8;

__device__ __forceinline__ unsigned short f2bf(float f) {
    union { float f; uint32_t u; } v; v.f = f;
    uint32_t u = v.u;
    u += 0x7fffu + ((u >> 16) & 1u);   // RNE (finite data, no NaN handling needed)
    return (unsigned short)(u >> 16);
}

// ---------------- Kernel 1a: W f32 -> bf16 ----------------
__global__ __launch_bounds__(256) void convert_w(const float* __restrict__ in,
                                                 unsigned short* __restrict__ out, int n4) {
    int i = blockIdx.x * blockDim.x + threadIdx.x;
    int stride = gridDim.x * blockDim.x;
    for (; i < n4; i += stride) {
        float4 v = ((const float4*)in)[i];
        ushort4 o;
        o.x = f2bf(v.x); o.y = f2bf(v.y); o.z = f2bf(v.z); o.w = f2bf(v.w);
        ((ushort4*)out)[i] = o;
    }
}

// ------- Kernel 1b: per-token x f32 -> bf16 + xa[s,r] = x[s,:] . A[idx[s],r,:] -------
__global__ __launch_bounds__(256) void xa_convert(const float* __restrict__ x,
                                                  const float* __restrict__ A,
                                                  const int* __restrict__ widx,
                                                  unsigned short* __restrict__ xbf,
                                                  float* __restrict__ xa) {
    int s = blockIdx.x;
    int t = threadIdx.x;
    int a = widx[s];
    const float* xrow = x + (size_t)s * IN_DIM;
    const float* Ab = A + (size_t)a * R_DIM * IN_DIM;

    float acc[R_DIM];
#pragma unroll
    for (int r = 0; r < R_DIM; ++r) acc[r] = 0.f;

#pragma unroll
    for (int it = 0; it < IN_DIM / (256 * 4); ++it) {
        int i = (it * 256 + t) * 4;
        float4 xv = *(const float4*)(xrow + i);
        ushort4 o;
        o.x = f2bf(xv.x); o.y = f2bf(xv.y); o.z = f2bf(xv.z); o.w = f2bf(xv.w);
        *(ushort4*)(xbf + (size_t)s * IN_DIM + i) = o;
#pragma unroll
        for (int r = 0; r < R_DIM; ++r) {
            float4 av = *(const float4*)(Ab + r * IN_DIM + i);
            acc[r] += xv.x * av.x + xv.y * av.y + xv.z * av.z + xv.w * av.w;
        }
    }
    // wave reduce each r
#pragma unroll
    for (int off = 32; off > 0; off >>= 1)
#pragma unroll
        for (int r = 0; r < R_DIM; ++r)
            acc[r] += __shfl_down(acc[r], off, 64);

    __shared__ float red[4][R_DIM];
    int lane = t & 63, w = t >> 6;
    if (lane == 0) {
#pragma unroll
        for (int r = 0; r < R_DIM; ++r) red[w][r] = acc[r];
    }
    __syncthreads();
    if (t < R_DIM)
        xa[(size_t)s * R_DIM + t] = red[0][t] + red[1][t] + red[2][t] + red[3][t];
}

// ---------------- Kernel 2: bf16 MFMA GEMM + fused LoRA-B/bias epilogue ----------------
__device__ __forceinline__ void gload_lds16(const void* g, void* l) {
    __builtin_amdgcn_global_load_lds(
        (const __attribute__((address_space(1))) unsigned int*)(uintptr_t)g,
        (__attribute__((address_space(3))) unsigned int*)(unsigned int)(uintptr_t)l,
        16, 0, 0);
}

__global__ __launch_bounds__(256) void gemm_fused(const unsigned short* __restrict__ Xb,
                                                  const unsigned short* __restrict__ Wb,
                                                  const float* __restrict__ bias,
                                                  const float* __restrict__ xa,
                                                  const float* __restrict__ Bm,
                                                  const int* __restrict__ widx,
                                                  float* __restrict__ out) {
    __shared__ unsigned short As[128 * 32];
    __shared__ unsigned short Bs[128 * 32];

    const int nTN = OUT_DIM / 128;              // 32
    const int nT = (S_DIM / 128) * nTN;         // 2048 (% 8 == 0 -> bijective swizzle)
    int bid = blockIdx.x;
    int per = nT >> 3;
    int swz = (bid & 7) * per + (bid >> 3);
    int tm = swz / nTN, tn = swz % nTN;
    int rowBase = tm * 128, colBase = tn * 128;

    int t = threadIdx.x;
    int lane = t & 63;
    int wid = t >> 6;
    int wm = wid >> 1, wn = wid & 1;            // 2x2 wave grid, each wave 64x64

    // staging: thread t copies 16B (8 bf16); row = t/4, k-col = (t%4)*8
    int srow = t >> 2;
    int scol = (t & 3) * 8;
    const unsigned short* xs0 = Xb + (size_t)(rowBase + srow) * IN_DIM + scol;
    const unsigned short* ws0 = Wb + (size_t)(colBase + srow) * IN_DIM + scol;

    f32x4 acc[4][4];
#pragma unroll
    for (int m = 0; m < 4; m++)
#pragma unroll
        for (int n = 0; n < 4; n++)
#pragma unroll
            for (int j = 0; j < 4; j++) acc[m][n][j] = 0.f;

    int frow = lane & 15;
    int fk = (lane >> 4) * 8;

    for (int kt = 0; kt < IN_DIM; kt += 32) {
        gload_lds16(xs0 + kt, &As[t * 8]);
        gload_lds16(xs0 + (size_t)64 * IN_DIM + kt, &As[64 * 32 + t * 8]);
        gload_lds16(ws0 + kt, &Bs[t * 8]);
        gload_lds16(ws0 + (size_t)64 * IN_DIM + kt, &Bs[64 * 32 + t * 8]);
        __syncthreads();

        bf16x8 af[4], bfr[4];
#pragma unroll
        for (int m = 0; m < 4; m++)
            af[m] = *(const bf16x8*)&As[(wm * 64 + m * 16 + frow) * 32 + fk];
#pragma unroll
        for (int n = 0; n < 4; n++)
            bfr[n] = *(const bf16x8*)&Bs[(wn * 64 + n * 16 + frow) * 32 + fk];
#pragma unroll
        for (int m = 0; m < 4; m++)
#pragma unroll
            for (int n = 0; n < 4; n++)
                acc[m][n] = __builtin_amdgcn_mfma_f32_16x16x32_bf16(af[m], bfr[n], acc[m][n], 0, 0, 0);
        __syncthreads();
    }

    // epilogue: out = acc + bias + 0.5 * (xa[row,:] . B[idx[row], col, :])
    int cb = colBase + wn * 64;
    int rb = rowBase + wm * 64;
    float biasv[4];
#pragma unroll
    for (int n = 0; n < 4; n++) biasv[n] = bias[cb + n * 16 + frow];

#pragma unroll
    for (int m = 0; m < 4; m++) {
#pragma unroll
        for (int rg = 0; rg < 4; rg++) {
            int row = rb + m * 16 + ((lane >> 4) << 2) + rg;
            int a = widx[row];
            const float* xr = xa + (size_t)row * R_DIM;
            f32x4 x0 = *(const f32x4*)xr;
            f32x4 x1 = *(const f32x4*)(xr + 4);
            f32x4 x2 = *(const f32x4*)(xr + 8);
            f32x4 x3 = *(const f32x4*)(xr + 12);
            const float* Bbase = Bm + (size_t)a * OUT_DIM * R_DIM;
            float* orow = out + (size_t)row * OUT_DIM;
#pragma unroll
            for (int n = 0; n < 4; n++) {
                int col = cb + n * 16 + frow;
                const float* Br = Bbase + (size_t)col * R_DIM;
                f32x4 b0 = *(const f32x4*)Br;
                f32x4 b1 = *(const f32x4*)(Br + 4);
                f32x4 b2 = *(const f32x4*)(Br + 8);
                f32x4 b3 = *(const f32x4*)(Br + 12);
                float l = x0[0] * b0[0] + x0[1] * b0[1] + x0[2] * b0[2] + x0[3] * b0[3]
                        + x1[0] * b1[0] + x1[1] * b1[1] + x1[2] * b1[2] + x1[3] * b1[3]
                        + x2[0] * b2[0] + x2[1] * b2[1] + x2[2] * b2[2] + x2[3] * b2[3]
                        + x3[0] * b3[0] + x3[1] * b3[1] + x3[2] * b3[2] + x3[3] * b3[3];
                orow[col] = acc[m][n][rg] + biasv[n] + SCALING * l;
            }
        }
    }
}

extern "C" void kernel_launch(void* const* d_in, const int* in_sizes, int n_in,
                              void* d_out, int out_size, void* d_ws, size_t ws_size,
                              hipStream_t stream) {
    const float* x = (const float*)d_in[0];
    const float* W = (const float*)d_in[1];
    const float* bias = (const float*)d_in[2];
    const float* Abuf = (const float*)d_in[3];
    const float* Bbuf = (const float*)d_in[4];   // [1, A, OUT, R] -> [A][OUT][R]
    const int* widx = (const int*)d_in[5];
    float* out = (float*)d_out;

    size_t xbf_elems = (size_t)S_DIM * IN_DIM;
    size_t wbf_elems = (size_t)OUT_DIM * IN_DIM;
    size_t need = xbf_elems * 2 + wbf_elems * 2 + (size_t)S_DIM * R_DIM * 4;
    if (ws_size < need) return;  // workspace too small: fail loudly via validation

    unsigned short* xbf = (unsigned short*)d_ws;
    unsigned short* wbf = xbf + xbf_elems;
    float* xa = (float*)(wbf + wbf_elems);

    convert_w<<<2048, 256, 0, stream>>>(W, wbf, (int)(wbf_elems / 4));
    xa_convert<<<S_DIM, 256, 0, stream>>>(x, Abuf, widx, xbf, xa);
    gemm_fused<<<2048, 256, 0, stream>>>(xbf, wbf, bias, xa, Bbuf, widx, out);
}

// Round 2
// 497.254 us; speedup vs baseline: 1.7183x; 1.7183x over previous
//
#include <hip/hip_runtime.h>
#include <stdint.h>

#define S_DIM 8192
#define IN_DIM 4096
#define OUT_DIM 4096
#define R_DIM 16
#define SCALING 0.5f

#define BM 256
#define BN 256
#define BK 64
#define NT (IN_DIM / BK)   // 64 K-tiles
#define HALF_E 8192        // elements per half-slot (128 rows x 64 cols)

typedef __attribute__((ext_vector_type(4))) float f32x4;
typedef __attribute__((ext_vector_type(8))) __bf16 bf16x8;

__device__ __forceinline__ unsigned short f2bf(float f) {
    union { float f; uint32_t u; } v; v.f = f;
    uint32_t u = v.u;
    u += 0x7fffu + ((u >> 16) & 1u);   // RNE
    return (unsigned short)(u >> 16);
}

// ---------------- Kernel 1a: W f32 -> bf16 ----------------
__global__ __launch_bounds__(256) void convert_w(const float* __restrict__ in,
                                                 unsigned short* __restrict__ out, int n4) {
    int i = blockIdx.x * blockDim.x + threadIdx.x;
    int stride = gridDim.x * blockDim.x;
    for (; i < n4; i += stride) {
        float4 v = ((const float4*)in)[i];
        ushort4 o;
        o.x = f2bf(v.x); o.y = f2bf(v.y); o.z = f2bf(v.z); o.w = f2bf(v.w);
        ((ushort4*)out)[i] = o;
    }
}

// ------- Kernel 1b: x f32 -> bf16 + xa[s,r] = x[s,:] . A[idx[s],r,:] -------
__global__ __launch_bounds__(256) void xa_convert(const float* __restrict__ x,
                                                  const float* __restrict__ A,
                                                  const int* __restrict__ widx,
                                                  unsigned short* __restrict__ xbf,
                                                  float* __restrict__ xa) {
    int s = blockIdx.x;
    int t = threadIdx.x;
    int a = widx[s];
    const float* xrow = x + (size_t)s * IN_DIM;
    const float* Ab = A + (size_t)a * R_DIM * IN_DIM;

    float acc[R_DIM];
#pragma unroll
    for (int r = 0; r < R_DIM; ++r) acc[r] = 0.f;

#pragma unroll
    for (int it = 0; it < IN_DIM / (256 * 4); ++it) {
        int i = (it * 256 + t) * 4;
        float4 xv = *(const float4*)(xrow + i);
        ushort4 o;
        o.x = f2bf(xv.x); o.y = f2bf(xv.y); o.z = f2bf(xv.z); o.w = f2bf(xv.w);
        *(ushort4*)(xbf + (size_t)s * IN_DIM + i) = o;
#pragma unroll
        for (int r = 0; r < R_DIM; ++r) {
            float4 av = *(const float4*)(Ab + r * IN_DIM + i);
            acc[r] += xv.x * av.x + xv.y * av.y + xv.z * av.z + xv.w * av.w;
        }
    }
#pragma unroll
    for (int off = 32; off > 0; off >>= 1)
#pragma unroll
        for (int r = 0; r < R_DIM; ++r)
            acc[r] += __shfl_down(acc[r], off, 64);

    __shared__ float red[4][R_DIM];
    int lane = t & 63, w = t >> 6;
    if (lane == 0) {
#pragma unroll
        for (int r = 0; r < R_DIM; ++r) red[w][r] = acc[r];
    }
    __syncthreads();
    if (t < R_DIM)
        xa[(size_t)s * R_DIM + t] = red[0][t] + red[1][t] + red[2][t] + red[3][t];
}

// ---------------- Kernel 2: 256x256 bf16 MFMA GEMM, counted-vmcnt pipeline ----------------
__device__ __forceinline__ void gload_lds16(const void* g, void* l) {
    __builtin_amdgcn_global_load_lds(
        (const __attribute__((address_space(1))) unsigned int*)(uintptr_t)g,
        (__attribute__((address_space(3))) unsigned int*)(unsigned int)(uintptr_t)l,
        16, 0, 0);
}

// LDS layout: slot(p, op, h) = p*32768 + op*16384 + h*8192 elements (p=parity, op: 0=A,1=B, h=half)
// Within a half: linear [row(128)][64 elems]; byte col is XOR-swizzled: stored_colbyte = colbyte ^ ((row&7)<<4).
// Staging writes linearly (global_load_lds) from a pre-swizzled GLOBAL source; reads apply the same XOR.

__global__ __launch_bounds__(512, 2) void gemm256(const unsigned short* __restrict__ Xb,
                                                  const unsigned short* __restrict__ Wb,
                                                  const float* __restrict__ bias,
                                                  const float* __restrict__ xa,
                                                  const float* __restrict__ Bm,
                                                  const int* __restrict__ widx,
                                                  float* __restrict__ out) {
    extern __shared__ unsigned short lds[];

    const int nTN = OUT_DIM / BN;           // 16
    const int nT = (S_DIM / BM) * nTN;      // 512 (%8==0 -> bijective XCD swizzle)
    int bid = blockIdx.x;
    int per = nT >> 3;                      // 64
    int swz = (bid & 7) * per + (bid >> 3);
    int tm = swz >> 4, tn = swz & 15;
    int rowBase = tm * BM, colBase = tn * BN;

    int t = threadIdx.x;
    int lane = t & 63;
    int wid = t >> 6;
    int wm = wid >> 2;                      // 0..1 (M half)
    int wn = wid & 3;                       // 0..3 (N quarter)
    int frow = lane & 15;
    int fkb = (lane >> 4) << 4;             // byte chunk base {0,16,32,48}

    // staging: thread t -> row sub=t/8 (+i*64), 16B at colbyte (t%8)*16, source pre-swizzled
    int sub = t >> 3;                       // 0..63
    int scol = ((((t & 7) << 4)) ^ ((sub & 7) << 4)) >> 1;  // element col within BK

#define STAGE_TILE(kt, p) do {                                                             \
    int koff_ = (kt) * BK + scol;                                                          \
    _Pragma("unroll") for (int h_ = 0; h_ < 2; ++h_)                                       \
      _Pragma("unroll") for (int i_ = 0; i_ < 2; ++i_)                                     \
        gload_lds16(Xb + (size_t)(rowBase + h_ * 128 + i_ * 64 + sub) * IN_DIM + koff_,    \
                    &lds[(p) * 32768 + h_ * HALF_E + i_ * 4096 + t * 8]);                  \
    _Pragma("unroll") for (int h_ = 0; h_ < 2; ++h_)                                       \
      _Pragma("unroll") for (int i_ = 0; i_ < 2; ++i_)                                     \
        gload_lds16(Wb + (size_t)(colBase + h_ * 128 + i_ * 64 + sub) * IN_DIM + koff_,    \
                    &lds[(p) * 32768 + 16384 + h_ * HALF_E + i_ * 4096 + t * 8]);          \
  } while (0)

    f32x4 acc[8][4];
#pragma unroll
    for (int m = 0; m < 8; m++)
#pragma unroll
        for (int n = 0; n < 4; n++)
#pragma unroll
            for (int j = 0; j < 4; j++) acc[m][n][j] = 0.f;

#define LOAD_A(p, mh)                                                                      \
    _Pragma("unroll") for (int mm = 0; mm < 4; mm++)                                       \
      _Pragma("unroll") for (int ks = 0; ks < 2; ks++) {                                   \
        int r_ = ((mh) * 4 + mm) * 16 + frow;                                              \
        int c_ = (fkb + ks * 64) ^ ((r_ & 7) << 4);                                        \
        afr[mm][ks] = *(const bf16x8*)&lds[(p) * 32768 + wm * HALF_E + r_ * 64 + (c_ >> 1)]; \
      }

#define LOAD_B(p, nh)                                                                      \
    _Pragma("unroll") for (int nn = 0; nn < 2; nn++)                                       \
      _Pragma("unroll") for (int ks = 0; ks < 2; ks++) {                                   \
        int r_ = (wn & 1) * 64 + ((nh) * 2 + nn) * 16 + frow;                              \
        int c_ = (fkb + ks * 64) ^ ((r_ & 7) << 4);                                        \
        bfr[nn][ks] = *(const bf16x8*)&lds[(p) * 32768 + 16384 + (wn >> 1) * HALF_E + r_ * 64 + (c_ >> 1)]; \
      }

#define MFMA_Q(mh, nh)                                                                     \
    __builtin_amdgcn_s_setprio(1);                                                         \
    _Pragma("unroll") for (int mm = 0; mm < 4; mm++)                                       \
      _Pragma("unroll") for (int nn = 0; nn < 2; nn++)                                     \
        _Pragma("unroll") for (int ks = 0; ks < 2; ks++)                                   \
          acc[(mh) * 4 + mm][(nh) * 2 + nn] = __builtin_amdgcn_mfma_f32_16x16x32_bf16(     \
              afr[mm][ks], bfr[nn][ks], acc[(mh) * 4 + mm][(nh) * 2 + nn], 0, 0, 0);       \
    __builtin_amdgcn_s_setprio(0);

#define COMPUTE_TILE(p) do {                                                               \
    bf16x8 afr[4][2], bfr[2][2];                                                           \
    LOAD_A(p, 0) LOAD_B(p, 0) MFMA_Q(0, 0)                                                 \
    LOAD_B(p, 1) MFMA_Q(0, 1)                                                              \
    LOAD_A(p, 1) MFMA_Q(1, 1)                                                              \
    LOAD_B(p, 0) MFMA_Q(1, 0)                                                              \
  } while (0)

    // prologue: stage tile 0 into parity 0
    STAGE_TILE(0, 0);

    for (int it = 0; it < NT / 2; ++it) {
        int t0 = 2 * it;
        // ---- group A: stage tile t0+1 (parity1), compute tile t0 (parity0)
        __builtin_amdgcn_s_barrier();                 // all waves done reading parity1
        asm volatile("" ::: "memory");
        STAGE_TILE(t0 + 1, 1);
        asm volatile("s_waitcnt vmcnt(8)" ::: "memory");  // tile t0 (oldest 8 loads) complete
        __builtin_amdgcn_s_barrier();                 // tile t0 visible to all waves
        asm volatile("" ::: "memory");
        COMPUTE_TILE(0);
        // ---- group B: stage tile t0+2 (parity0), compute tile t0+1 (parity1)
        __builtin_amdgcn_s_barrier();                 // all waves done reading parity0
        asm volatile("" ::: "memory");
        if (t0 + 2 < NT) {
            STAGE_TILE(t0 + 2, 0);
            asm volatile("s_waitcnt vmcnt(8)" ::: "memory");  // tile t0+1 complete
        } else {
            asm volatile("s_waitcnt vmcnt(0)" ::: "memory");  // last tile: drain
        }
        __builtin_amdgcn_s_barrier();
        asm volatile("" ::: "memory");
        COMPUTE_TILE(1);
    }

    // ---- epilogue: out = acc + bias + 0.5 * (xa[row,:] . B[idx[row], col, :])
    int cb = colBase + wn * 64;
    int rb = rowBase + wm * 128;
    int rquad = (lane >> 4) << 2;
    float biasv[4];
#pragma unroll
    for (int n = 0; n < 4; n++) biasv[n] = bias[cb + n * 16 + frow];

#pragma unroll
    for (int m = 0; m < 8; m++) {
#pragma unroll
        for (int rg = 0; rg < 4; rg++) {
            int row = rb + m * 16 + rquad + rg;
            int a = widx[row];
            const float* xr = xa + (size_t)row * R_DIM;
            f32x4 x0 = *(const f32x4*)xr;
            f32x4 x1 = *(const f32x4*)(xr + 4);
            f32x4 x2 = *(const f32x4*)(xr + 8);
            f32x4 x3 = *(const f32x4*)(xr + 12);
            const float* Bbase = Bm + (size_t)a * OUT_DIM * R_DIM;
            float* orow = out + (size_t)row * OUT_DIM;
#pragma unroll
            for (int n = 0; n < 4; n++) {
                int col = cb + n * 16 + frow;
                const float* Br = Bbase + (size_t)col * R_DIM;
                f32x4 b0 = *(const f32x4*)Br;
                f32x4 b1 = *(const f32x4*)(Br + 4);
                f32x4 b2 = *(const f32x4*)(Br + 8);
                f32x4 b3 = *(const f32x4*)(Br + 12);
                float l = x0[0] * b0[0] + x0[1] * b0[1] + x0[2] * b0[2] + x0[3] * b0[3]
                        + x1[0] * b1[0] + x1[1] * b1[1] + x1[2] * b1[2] + x1[3] * b1[3]
                        + x2[0] * b2[0] + x2[1] * b2[1] + x2[2] * b2[2] + x2[3] * b2[3]
                        + x3[0] * b3[0] + x3[1] * b3[1] + x3[2] * b3[2] + x3[3] * b3[3];
                orow[col] = acc[m][n][rg] + biasv[n] + SCALING * l;
            }
        }
    }
}

extern "C" void kernel_launch(void* const* d_in, const int* in_sizes, int n_in,
                              void* d_out, int out_size, void* d_ws, size_t ws_size,
                              hipStream_t stream) {
    const float* x = (const float*)d_in[0];
    const float* W = (const float*)d_in[1];
    const float* bias = (const float*)d_in[2];
    const float* Abuf = (const float*)d_in[3];
    const float* Bbuf = (const float*)d_in[4];   // [1, A, OUT, R]
    const int* widx = (const int*)d_in[5];
    float* out = (float*)d_out;

    size_t xbf_elems = (size_t)S_DIM * IN_DIM;
    size_t wbf_elems = (size_t)OUT_DIM * IN_DIM;
    size_t need = xbf_elems * 2 + wbf_elems * 2 + (size_t)S_DIM * R_DIM * 4;
    if (ws_size < need) return;

    unsigned short* xbf = (unsigned short*)d_ws;
    unsigned short* wbf = xbf + xbf_elems;
    float* xa = (float*)(wbf + wbf_elems);

    // allow 128 KiB dynamic LDS (deterministic, idempotent)
    hipFuncSetAttribute(reinterpret_cast<const void*>(gemm256),
                        hipFuncAttributeMaxDynamicSharedMemorySize, 131072);

    convert_w<<<2048, 256, 0, stream>>>(W, wbf, (int)(wbf_elems / 4));
    xa_convert<<<S_DIM, 256, 0, stream>>>(x, Abuf, widx, xbf, xa);
    gemm256<<<512, 512, 131072, stream>>>(xbf, wbf, bias, xa, Bbuf, widx, out);
}

// Round 3
// 356.329 us; speedup vs baseline: 2.3979x; 1.3955x over previous
//
#include <hip/hip_runtime.h>
#include <stdint.h>

#define S_DIM 8192
#define IN_DIM 4096
#define OUT_DIM 4096
#define SCALING 0.5f

typedef __attribute__((ext_vector_type(4))) float f32x4;
typedef __attribute__((ext_vector_type(8))) __bf16 bf16x8;

__device__ __forceinline__ unsigned short f2bf(float f) {
    union { float f; uint32_t u; } v; v.f = f;
    uint32_t u = v.u;
    u += 0x7fffu + ((u >> 16) & 1u);   // RNE
    return (unsigned short)(u >> 16);
}

// ---------------- Kernel 1: W f32 -> bf16 (grid-stride) ----------------
__global__ __launch_bounds__(256) void convert_w(const float* __restrict__ in,
                                                 unsigned short* __restrict__ out, int n4) {
    int i = blockIdx.x * blockDim.x + threadIdx.x;
    int stride = gridDim.x * blockDim.x;
    for (; i < n4; i += stride) {
        float4 v = ((const float4*)in)[i];
        ushort4 o;
        o.x = f2bf(v.x); o.y = f2bf(v.y); o.z = f2bf(v.z); o.w = f2bf(v.w);
        ((ushort4*)out)[i] = o;
    }
}

// ------- Kernel 2: x f32->bf16 + xa_sel[s,r] = x[s,:] . A[widx[s],r,:] via MFMA -------
// 256 blocks x 32 tokens; 8 waves: wr=w&1 (token half), wc=w>>1 (j-quarter of 128)
__global__ __launch_bounds__(512) void xak(const float* __restrict__ x,
                                           const float* __restrict__ A,
                                           const int* __restrict__ widx,
                                           unsigned short* __restrict__ xbf,
                                           float* __restrict__ xa_sel) {
    __shared__ unsigned short xs[32 * 64];    // 4 KB, rows 128B, swizzled
    __shared__ unsigned short as_[128 * 64];  // 16 KB, rows 128B, swizzled
    int s0 = blockIdx.x * 32;
    int t = threadIdx.x;
    int lane = t & 63, w = t >> 6;
    int wr = w & 1, wc = w >> 1;
    int frow = lane & 15, koct = lane >> 4;

    f32x4 acc[2];
#pragma unroll
    for (int n = 0; n < 2; ++n)
#pragma unroll
        for (int j = 0; j < 4; ++j) acc[n][j] = 0.f;

    int xrow = t >> 4, xf4 = t & 15;
    const float* xsrc = x + (size_t)(s0 + xrow) * IN_DIM + xf4 * 4;
    unsigned short* xdst = xbf + (size_t)(s0 + xrow) * IN_DIM + xf4 * 4;
    int xsd = xrow * 64 + ((xf4 * 4) ^ ((xrow & 7) << 3));

    for (int kt = 0; kt < 64; ++kt) {
        int k0 = kt * 64;
        __syncthreads();   // prev tile reads done
        {
            float4 xv = *(const float4*)(xsrc + k0);
            ushort4 o;
            o.x = f2bf(xv.x); o.y = f2bf(xv.y); o.z = f2bf(xv.z); o.w = f2bf(xv.w);
            *(ushort4*)(xdst + k0) = o;
            *(ushort4*)&xs[xsd] = o;
        }
#pragma unroll
        for (int i = 0; i < 4; ++i) {
            int c = i * 512 + t;
            int aj = c >> 4, af4 = c & 15;
            float4 av = *(const float4*)(A + (size_t)aj * IN_DIM + k0 + af4 * 4);
            ushort4 o;
            o.x = f2bf(av.x); o.y = f2bf(av.y); o.z = f2bf(av.z); o.w = f2bf(av.w);
            *(ushort4*)&as_[aj * 64 + ((af4 * 4) ^ ((aj & 7) << 3))] = o;
        }
        __syncthreads();   // writes visible
        bf16x8 xf[2], af[2][2];
#pragma unroll
        for (int ks = 0; ks < 2; ++ks) {
            int r = wr * 16 + frow;
            int ch = koct + ks * 4;
            xf[ks] = *(const bf16x8*)&xs[r * 64 + ((ch ^ (r & 7)) << 3)];
        }
#pragma unroll
        for (int nn = 0; nn < 2; ++nn)
#pragma unroll
            for (int ks = 0; ks < 2; ++ks) {
                int rj = wc * 32 + nn * 16 + frow;
                int ch = koct + ks * 4;
                af[nn][ks] = *(const bf16x8*)&as_[rj * 64 + ((ch ^ (rj & 7)) << 3)];
            }
#pragma unroll
        for (int nn = 0; nn < 2; ++nn)
#pragma unroll
            for (int ks = 0; ks < 2; ++ks)
                acc[nn] = __builtin_amdgcn_mfma_f32_16x16x32_bf16(xf[ks], af[nn][ks], acc[nn], 0, 0, 0);
    }
    // select + write xa_sel
#pragma unroll
    for (int rg = 0; rg < 4; ++rg) {
        int s = s0 + wr * 16 + koct * 4 + rg;
        int a = widx[s];
#pragma unroll
        for (int nn = 0; nn < 2; ++nn) {
            if (wc * 2 + nn == a)
                xa_sel[(size_t)s * 16 + frow] = acc[nn][rg];
        }
    }
}

// ---------------- Kernel 3: 256x256 bf16 MFMA GEMM, depth-3 counted-vmcnt pipeline ----------------
__device__ __forceinline__ void gload_lds16(const void* g, void* l) {
    __builtin_amdgcn_global_load_lds(
        (const __attribute__((address_space(1))) unsigned int*)(uintptr_t)g,
        (__attribute__((address_space(3))) unsigned int*)(unsigned int)(uintptr_t)l,
        16, 0, 0);
}

// 4 buffers x 32KB (A 16KB: 256 rows x 64B; B 16KB). BK=32. Swizzle: 16B-chunk idx ^= (row>>1)&3.
#define VM8 asm volatile("s_waitcnt vmcnt(8)" ::: "memory")
#define VM4 asm volatile("s_waitcnt vmcnt(4)" ::: "memory")
#define VM0 asm volatile("s_waitcnt vmcnt(0)" ::: "memory")
#define VMNOP do {} while (0)

__global__ __launch_bounds__(512, 2) void gemm256(const unsigned short* __restrict__ Xb,
                                                  const unsigned short* __restrict__ Wb,
                                                  const float* __restrict__ bias,
                                                  const float* __restrict__ xa,
                                                  const float* __restrict__ Bm,
                                                  const int* __restrict__ widx,
                                                  float* __restrict__ out) {
    extern __shared__ unsigned short lds[];

    const int nT = 512;                      // 32 x 16 tiles, %8==0 -> bijective XCD swizzle
    int bid = blockIdx.x;
    int swz = (bid & 7) * (nT >> 3) + (bid >> 3);
    int tm = swz >> 4, tn = swz & 15;
    int rowBase = tm * 256, colBase = tn * 256;

    int t = threadIdx.x;
    int lane = t & 63;
    int wid = t >> 6;
    int wm = wid >> 2;                       // 0..1 -> 128 rows
    int wn = wid & 3;                        // 0..3 -> 64 cols
    int frow = lane & 15;
    int koct = lane >> 4;                    // k-octet 0..3
    int wmBase = wm * 128, wnBase = wn * 64;

    // staging: chunk c = j*512+t -> row c>>2 (+128 for j=1), stored chunk c&3, kc = (c&3)^((row>>1)&3)
    int kcA = (t & 3) ^ ((t >> 3) & 3);
    const unsigned short* srcA0 = Xb + (size_t)(rowBase + (t >> 2)) * IN_DIM + kcA * 8;
    const unsigned short* srcB0 = Wb + (size_t)(colBase + (t >> 2)) * IN_DIM + kcA * 8;

#define STAGE_A(KEL, SB_) do { \
    gload_lds16(srcA0 + (KEL), &lds[(SB_) * 16384 + t * 8]); \
    gload_lds16(srcA0 + (size_t)128 * IN_DIM + (KEL), &lds[(SB_) * 16384 + 4096 + t * 8]); \
  } while (0)
#define STAGE_B(KEL, SB_) do { \
    gload_lds16(srcB0 + (KEL), &lds[(SB_) * 16384 + 8192 + t * 8]); \
    gload_lds16(srcB0 + (size_t)128 * IN_DIM + (KEL), &lds[(SB_) * 16384 + 12288 + t * 8]); \
  } while (0)

    f32x4 acc[8][4];
#pragma unroll
    for (int m = 0; m < 8; m++)
#pragma unroll
        for (int n = 0; n < 4; n++)
#pragma unroll
            for (int j = 0; j < 4; j++) acc[m][n][j] = 0.f;

#define LDA_PH(B_, MH, DST) \
    _Pragma("unroll") for (int mm = 0; mm < 4; ++mm) { \
      int r_ = wmBase + (MH) * 64 + mm * 16 + frow; \
      DST[mm] = *(const bf16x8*)&lds[(B_) * 16384 + r_ * 32 + ((koct ^ ((r_ >> 1) & 3)) << 3)]; \
    }
#define LDB_PH(B_, DST) \
    _Pragma("unroll") for (int nn = 0; nn < 4; ++nn) { \
      int r_ = wnBase + nn * 16 + frow; \
      DST[nn] = *(const bf16x8*)&lds[(B_) * 16384 + 8192 + r_ * 32 + ((koct ^ ((r_ >> 1) & 3)) << 3)]; \
    }
#define MFMA_PH(AF, BF, MH) \
    __builtin_amdgcn_s_setprio(1); \
    _Pragma("unroll") for (int mm = 0; mm < 4; ++mm) \
      _Pragma("unroll") for (int nn = 0; nn < 4; ++nn) \
        acc[(MH) * 4 + mm][nn] = __builtin_amdgcn_mfma_f32_16x16x32_bf16( \
            AF[mm], BF[nn], acc[(MH) * 4 + mm][nn], 0, 0, 0); \
    __builtin_amdgcn_s_setprio(0);

#define K_ITER(KEL, B_, SB_, STG, VMOP) do { \
    bf16x8 a0_[4], a1_[4], bq_[4]; \
    if (STG) STAGE_A((KEL) + 96, SB_); \
    LDA_PH(B_, 0, a0_); \
    LDB_PH(B_, bq_); \
    __builtin_amdgcn_s_barrier(); asm volatile("" ::: "memory"); \
    MFMA_PH(a0_, bq_, 0); \
    if (STG) STAGE_B((KEL) + 96, SB_); \
    LDA_PH(B_, 1, a1_); \
    VMOP; \
    __builtin_amdgcn_s_barrier(); asm volatile("" ::: "memory"); \
    MFMA_PH(a1_, bq_, 1); \
    __builtin_amdgcn_s_barrier(); asm volatile("" ::: "memory"); \
  } while (0)

    // prologue: stage tiles 0,1,2 into bufs 0,1,2
    STAGE_A(0, 0); STAGE_B(0, 0);
    STAGE_A(32, 1); STAGE_B(32, 1);
    STAGE_A(64, 2); STAGE_B(64, 2);
    VM8;  // tile 0 complete (12 outstanding -> 8)
    __builtin_amdgcn_s_barrier(); asm volatile("" ::: "memory");

    int kel = 0;
#pragma unroll 1
    for (int it = 0; it < 31; ++it) {        // tiles 0..123
        K_ITER(kel, 0, 3, 1, VM8); kel += 32;
        K_ITER(kel, 1, 0, 1, VM8); kel += 32;
        K_ITER(kel, 2, 1, 1, VM8); kel += 32;
        K_ITER(kel, 3, 2, 1, VM8); kel += 32;
    }
    K_ITER(kel, 0, 3, 1, VM8); kel += 32;    // tile 124, stages 127
    K_ITER(kel, 1, 0, 0, VM4); kel += 32;    // tile 125
    K_ITER(kel, 2, 0, 0, VM0); kel += 32;    // tile 126
    K_ITER(kel, 3, 0, 0, VMNOP);             // tile 127

    // ---- epilogue: restage B-slice (128KB) + xa rows (16KB) into LDS ----
    float* fl = (float*)lds;
#pragma unroll
    for (int i = 0; i < 16; ++i) {
        int ci = i * 512 + t;
        int ba = ci >> 10, rem = ci & 1023;
        int bcol = rem >> 2, q = rem & 3;
        f32x4 v = *(const f32x4*)(Bm + ((size_t)ba * OUT_DIM + colBase + bcol) * 16 + q * 4);
        *(f32x4*)&fl[(ba * 256 + bcol) * 16 + ((q ^ ((bcol >> 1) & 3)) << 2)] = v;
    }
    {
        int row = t >> 1, half = t & 1;
        const float* src = xa + (size_t)(rowBase + row) * 16 + half * 8;
        *(f32x4*)&fl[32768 + row * 16 + half * 8] = *(const f32x4*)src;
        *(f32x4*)&fl[32768 + row * 16 + half * 8 + 4] = *(const f32x4*)(src + 4);
    }
    __syncthreads();

    int rquad = koct << 2;
    float biasv[4];
#pragma unroll
    for (int n = 0; n < 4; n++) biasv[n] = bias[colBase + wnBase + n * 16 + frow];

#pragma unroll
    for (int m = 0; m < 8; m++) {
#pragma unroll
        for (int rg = 0; rg < 4; rg++) {
            int lr = wmBase + m * 16 + rquad + rg;
            int grow = rowBase + lr;
            int a = widx[grow];
            f32x4 x0 = *(const f32x4*)&fl[32768 + lr * 16];
            f32x4 x1 = *(const f32x4*)&fl[32768 + lr * 16 + 4];
            f32x4 x2 = *(const f32x4*)&fl[32768 + lr * 16 + 8];
            f32x4 x3 = *(const f32x4*)&fl[32768 + lr * 16 + 12];
            float* orow = out + (size_t)grow * OUT_DIM;
#pragma unroll
            for (int n = 0; n < 4; n++) {
                int lc = wnBase + n * 16 + frow;
                int s = (lc >> 1) & 3;
                int bi = (a * 256 + lc) * 16;
                f32x4 b0 = *(const f32x4*)&fl[bi + ((0 ^ s) << 2)];
                f32x4 b1 = *(const f32x4*)&fl[bi + ((1 ^ s) << 2)];
                f32x4 b2 = *(const f32x4*)&fl[bi + ((2 ^ s) << 2)];
                f32x4 b3 = *(const f32x4*)&fl[bi + ((3 ^ s) << 2)];
                float l = x0[0]*b0[0] + x0[1]*b0[1] + x0[2]*b0[2] + x0[3]*b0[3]
                        + x1[0]*b1[0] + x1[1]*b1[1] + x1[2]*b1[2] + x1[3]*b1[3]
                        + x2[0]*b2[0] + x2[1]*b2[1] + x2[2]*b2[2] + x2[3]*b2[3]
                        + x3[0]*b3[0] + x3[1]*b3[1] + x3[2]*b3[2] + x3[3]*b3[3];
                orow[colBase + lc] = acc[m][n][rg] + biasv[n] + SCALING * l;
            }
        }
    }
}

extern "C" void kernel_launch(void* const* d_in, const int* in_sizes, int n_in,
                              void* d_out, int out_size, void* d_ws, size_t ws_size,
                              hipStream_t stream) {
    const float* x = (const float*)d_in[0];
    const float* W = (const float*)d_in[1];
    const float* bias = (const float*)d_in[2];
    const float* Abuf = (const float*)d_in[3];
    const float* Bbuf = (const float*)d_in[4];   // [1, A, OUT, R]
    const int* widx = (const int*)d_in[5];
    float* out = (float*)d_out;

    size_t xbf_elems = (size_t)S_DIM * IN_DIM;
    size_t wbf_elems = (size_t)OUT_DIM * IN_DIM;
    size_t need = xbf_elems * 2 + wbf_elems * 2 + (size_t)S_DIM * 16 * 4;
    if (ws_size < need) return;

    unsigned short* xbf = (unsigned short*)d_ws;
    unsigned short* wbf = xbf + xbf_elems;
    float* xa_sel = (float*)(wbf + wbf_elems);

    hipFuncSetAttribute(reinterpret_cast<const void*>(gemm256),
                        hipFuncAttributeMaxDynamicSharedMemorySize, 147456);

    convert_w<<<2048, 256, 0, stream>>>(W, wbf, (int)(wbf_elems / 4));
    xak<<<256, 512, 0, stream>>>(x, Abuf, widx, xbf, xa_sel);
    gemm256<<<512, 512, 147456, stream>>>(xbf, wbf, bias, xa_sel, Bbuf, widx, out);
}

// Round 4
// 343.946 us; speedup vs baseline: 2.4842x; 1.0360x over previous
//
#include <hip/hip_runtime.h>
#include <stdint.h>

#define S_DIM 8192
#define IN_DIM 4096
#define OUT_DIM 4096
#define SCALING 0.5f

typedef __attribute__((ext_vector_type(4))) float f32x4;
typedef __attribute__((ext_vector_type(8))) __bf16 bf16x8;

__device__ __forceinline__ unsigned short f2bf(float f) {
    union { float f; uint32_t u; } v; v.f = f;
    uint32_t u = v.u;
    u += 0x7fffu + ((u >> 16) & 1u);   // RNE
    return (unsigned short)(u >> 16);
}

// ---------------- Kernel 1: f32 -> bf16 (grid-stride; used for W and A) ----------------
__global__ __launch_bounds__(256) void convert_w(const float* __restrict__ in,
                                                 unsigned short* __restrict__ out, int n4) {
    int i = blockIdx.x * blockDim.x + threadIdx.x;
    int stride = gridDim.x * blockDim.x;
    for (; i < n4; i += stride) {
        float4 v = ((const float4*)in)[i];
        ushort4 o;
        o.x = f2bf(v.x); o.y = f2bf(v.y); o.z = f2bf(v.z); o.w = f2bf(v.w);
        ((ushort4*)out)[i] = o;
    }
}

// ------- Kernel 2: x f32->bf16 + xa_sel[s,r] = x[s,:] . A[widx[s],r,:] via MFMA -------
// 256 blocks x 32 tokens; 8 waves: wr=w&1 (token half), wc=w>>1 (j-quarter of 128)
__global__ __launch_bounds__(512) void xak(const float* __restrict__ x,
                                           const unsigned short* __restrict__ Abf,
                                           const int* __restrict__ widx,
                                           unsigned short* __restrict__ xbf,
                                           float* __restrict__ xa_sel) {
    __shared__ unsigned short xs[32 * 64];    // 4 KB, rows 128B, swizzled
    __shared__ unsigned short as_[128 * 64];  // 16 KB, rows 128B, swizzled
    int s0 = blockIdx.x * 32;
    int t = threadIdx.x;
    int lane = t & 63, w = t >> 6;
    int wr = w & 1, wc = w >> 1;
    int frow = lane & 15, koct = lane >> 4;

    f32x4 acc[2];
#pragma unroll
    for (int n = 0; n < 2; ++n)
#pragma unroll
        for (int j = 0; j < 4; ++j) acc[n][j] = 0.f;

    int xrow = t >> 4, xf4 = t & 15;
    const float* xsrc = x + (size_t)(s0 + xrow) * IN_DIM + xf4 * 4;
    unsigned short* xdst = xbf + (size_t)(s0 + xrow) * IN_DIM + xf4 * 4;
    int xsd = xrow * 64 + ((xf4 * 4) ^ ((xrow & 7) << 3));

    for (int kt = 0; kt < 64; ++kt) {
        int k0 = kt * 64;
        __syncthreads();   // prev tile reads done
        {
            float4 xv = *(const float4*)(xsrc + k0);
            ushort4 o;
            o.x = f2bf(xv.x); o.y = f2bf(xv.y); o.z = f2bf(xv.z); o.w = f2bf(xv.w);
            *(ushort4*)(xdst + k0) = o;
            *(ushort4*)&xs[xsd] = o;
        }
#pragma unroll
        for (int i = 0; i < 2; ++i) {
            int c = i * 512 + t;              // 0..1023
            int aj = c >> 3, ch = c & 7;      // row 0..127, 8-elem chunk
            bf16x8 av = *(const bf16x8*)(Abf + (size_t)aj * IN_DIM + k0 + ch * 8);
            *(bf16x8*)&as_[aj * 64 + (((ch) ^ (aj & 7)) << 3)] = av;
        }
        __syncthreads();   // writes visible
        bf16x8 xf[2], af[2][2];
#pragma unroll
        for (int ks = 0; ks < 2; ++ks) {
            int r = wr * 16 + frow;
            int ch = koct + ks * 4;
            xf[ks] = *(const bf16x8*)&xs[r * 64 + ((ch ^ (r & 7)) << 3)];
        }
#pragma unroll
        for (int nn = 0; nn < 2; ++nn)
#pragma unroll
            for (int ks = 0; ks < 2; ++ks) {
                int rj = wc * 32 + nn * 16 + frow;
                int ch = koct + ks * 4;
                af[nn][ks] = *(const bf16x8*)&as_[rj * 64 + ((ch ^ (rj & 7)) << 3)];
            }
#pragma unroll
        for (int nn = 0; nn < 2; ++nn)
#pragma unroll
            for (int ks = 0; ks < 2; ++ks)
                acc[nn] = __builtin_amdgcn_mfma_f32_16x16x32_bf16(xf[ks], af[nn][ks], acc[nn], 0, 0, 0);
    }
#pragma unroll
    for (int rg = 0; rg < 4; ++rg) {
        int s = s0 + wr * 16 + koct * 4 + rg;
        int a = widx[s];
#pragma unroll
        for (int nn = 0; nn < 2; ++nn) {
            if (wc * 2 + nn == a)
                xa_sel[(size_t)s * 16 + frow] = acc[nn][rg];
        }
    }
}

// ---------------- Kernel 3: 256x256 bf16 MFMA GEMM, BK=64, 4-phase counted-vmcnt ----------------
__device__ __forceinline__ void gload_lds16(const void* g, void* l) {
    __builtin_amdgcn_global_load_lds(
        (const __attribute__((address_space(1))) unsigned int*)(uintptr_t)g,
        (__attribute__((address_space(3))) unsigned int*)(unsigned int)(uintptr_t)l,
        16, 0, 0);
}

// 2 buffers x 64KB: A 32KB (256 rows x 128B), B 32KB. Swizzle: 16B-chunk idx ^= (row&7) (0-conflict, round-2 verified).
#define VM4 asm volatile("s_waitcnt vmcnt(4)" ::: "memory")
#define VM2 asm volatile("s_waitcnt vmcnt(2)" ::: "memory")
#define VM0 asm volatile("s_waitcnt vmcnt(0)" ::: "memory")
#define VMNOP do {} while (0)
#define BAR do { __builtin_amdgcn_s_barrier(); asm volatile("" ::: "memory"); } while (0)

__global__ __launch_bounds__(512, 2) void gemm256(const unsigned short* __restrict__ Xb,
                                                  const unsigned short* __restrict__ Wb,
                                                  const float* __restrict__ bias,
                                                  const float* __restrict__ xa,
                                                  const float* __restrict__ Bm,
                                                  const int* __restrict__ widx,
                                                  float* __restrict__ out) {
    extern __shared__ unsigned short lds[];

    const int nT = 512;                      // 32 x 16 tiles, %8==0 -> bijective XCD swizzle
    int bid = blockIdx.x;
    int swz = (bid & 7) * (nT >> 3) + (bid >> 3);
    int tm = swz >> 4, tn = swz & 15;
    int rowBase = tm * 256, colBase = tn * 256;

    int t = threadIdx.x;
    int lane = t & 63;
    int wid = t >> 6;
    int wm = wid >> 2;                       // 0..1 -> 128 rows
    int wn = wid & 3;                        // 0..3 -> 64 cols
    int frow = lane & 15;
    int koct = lane >> 4;                    // 16B chunk within K-half
    int wmBase = wm * 128, wnBase = wn * 64;

    // staging: thread t -> row t>>3, 16B dest chunk t&7; global source chunk (t&7)^(row&7)
    int srow = t >> 3;
    int schunk = ((t & 7) ^ (srow & 7)) << 3;   // element offset
    const unsigned short* srcA0 = Xb + (size_t)(rowBase + srow) * IN_DIM + schunk;
    const unsigned short* srcB0 = Wb + (size_t)(colBase + srow) * IN_DIM + schunk;

#define STAGE_AG(G_, KEL, Q_) \
    gload_lds16(srcA0 + (size_t)(G_) * 64 * IN_DIM + (KEL), &lds[(Q_) * 32768 + (G_) * 4096 + t * 8])
#define STAGE_BG(G_, KEL, Q_) \
    gload_lds16(srcB0 + (size_t)(G_) * 64 * IN_DIM + (KEL), &lds[(Q_) * 32768 + 16384 + (G_) * 4096 + t * 8])

    f32x4 acc[8][4];
#pragma unroll
    for (int m = 0; m < 8; m++)
#pragma unroll
        for (int n = 0; n < 4; n++)
#pragma unroll
            for (int j = 0; j < 4; j++) acc[m][n][j] = 0.f;

#define RD_A(P_, MH, KS, DST) \
    _Pragma("unroll") for (int mm = 0; mm < 4; ++mm) { \
      int r_ = wmBase + (MH) * 64 + mm * 16 + frow; \
      int ch_ = ((KS) * 4 + koct) ^ (r_ & 7); \
      DST[mm] = *(const bf16x8*)&lds[(P_) * 32768 + r_ * 64 + ch_ * 8]; \
    }
#define RD_B(P_, KS, DST) \
    _Pragma("unroll") for (int nn = 0; nn < 4; ++nn) { \
      int r_ = wnBase + nn * 16 + frow; \
      int ch_ = ((KS) * 4 + koct) ^ (r_ & 7); \
      DST[nn] = *(const bf16x8*)&lds[(P_) * 32768 + 16384 + r_ * 64 + ch_ * 8]; \
    }
#define MFMA16(AF, BF, MH) \
    __builtin_amdgcn_s_setprio(1); \
    _Pragma("unroll") for (int mm = 0; mm < 4; ++mm) \
      _Pragma("unroll") for (int nn = 0; nn < 4; ++nn) \
        acc[(MH) * 4 + mm][nn] = __builtin_amdgcn_mfma_f32_16x16x32_bf16( \
            AF[mm], BF[nn], acc[(MH) * 4 + mm][nn], 0, 0, 0); \
    __builtin_amdgcn_s_setprio(0);

// Per tile t (buffer P_), stage tile t+1 into Q_ at ph0/ph1.
// ph0 vmcnt(4): publishes A1,A3(t) for ph1 reads. ph3 vmcnt(2): publishes first-6 of t+1 for next ph0.
#define TILE(P_, Q_, KN_, STG_, VMA_, VMB_) do { \
    bf16x8 a0_[4], a1_[4], b0_[4], b1_[4]; \
    RD_A(P_, 0, 0, a0_); RD_B(P_, 0, b0_); \
    if (STG_) { STAGE_AG(0, KN_, Q_); STAGE_AG(2, KN_, Q_); STAGE_BG(0, KN_, Q_); STAGE_BG(1, KN_, Q_); } \
    VMA_; BAR; MFMA16(a0_, b0_, 0); BAR; \
    RD_A(P_, 1, 0, a1_); \
    if (STG_) { STAGE_BG(2, KN_, Q_); STAGE_BG(3, KN_, Q_); STAGE_AG(1, KN_, Q_); STAGE_AG(3, KN_, Q_); } \
    BAR; MFMA16(a1_, b0_, 1); BAR; \
    RD_A(P_, 0, 1, a0_); RD_B(P_, 1, b1_); \
    BAR; MFMA16(a0_, b1_, 0); BAR; \
    RD_A(P_, 1, 1, a1_); \
    VMB_; BAR; MFMA16(a1_, b1_, 1); BAR; \
  } while (0)

    // prologue: stage tile 0 (order: A0,A2,B0,B1,B2,B3,A1,A3), publish first 6
    STAGE_AG(0, 0, 0); STAGE_AG(2, 0, 0); STAGE_BG(0, 0, 0); STAGE_BG(1, 0, 0);
    STAGE_BG(2, 0, 0); STAGE_BG(3, 0, 0); STAGE_AG(1, 0, 0); STAGE_AG(3, 0, 0);
    VM2; BAR;

    int kel = 0;
#pragma unroll 1
    for (int it = 0; it < 31; ++it) {        // tiles 0..61
        TILE(0, 1, kel + 64, 1, VM4, VM2); kel += 64;
        TILE(1, 0, kel + 64, 1, VM4, VM2); kel += 64;
    }
    TILE(0, 1, kel + 64, 1, VM4, VM2); kel += 64;   // tile 62, stages 63
    TILE(1, 0, 0, 0, VM0, VMNOP);                    // tile 63

    // ---- epilogue: restage B-slice (128KB) + xa rows (16KB) into LDS ----
    float* fl = (float*)lds;
#pragma unroll
    for (int i = 0; i < 16; ++i) {
        int ci = i * 512 + t;
        int ba = ci >> 10, rem = ci & 1023;
        int bcol = rem >> 2, q = rem & 3;
        f32x4 v = *(const f32x4*)(Bm + ((size_t)ba * OUT_DIM + colBase + bcol) * 16 + q * 4);
        *(f32x4*)&fl[(ba * 256 + bcol) * 16 + ((q ^ ((bcol >> 1) & 3)) << 2)] = v;
    }
    {
        int row = t >> 1, half = t & 1;
        const float* src = xa + (size_t)(rowBase + row) * 16 + half * 8;
        *(f32x4*)&fl[32768 + row * 16 + half * 8] = *(const f32x4*)src;
        *(f32x4*)&fl[32768 + row * 16 + half * 8 + 4] = *(const f32x4*)(src + 4);
    }
    __syncthreads();

    int rquad = koct << 2;
    float biasv[4];
#pragma unroll
    for (int n = 0; n < 4; n++) biasv[n] = bias[colBase + wnBase + n * 16 + frow];

#pragma unroll
    for (int m = 0; m < 8; m++) {
#pragma unroll
        for (int rg = 0; rg < 4; rg++) {
            int lr = wmBase + (m >> 2) * 64 + (m & 3) * 16 + rquad + rg;   // frag (mh=m>>2, mm=m&3)
            int grow = rowBase + lr;
            int a = widx[grow];
            f32x4 x0 = *(const f32x4*)&fl[32768 + lr * 16];
            f32x4 x1 = *(const f32x4*)&fl[32768 + lr * 16 + 4];
            f32x4 x2 = *(const f32x4*)&fl[32768 + lr * 16 + 8];
            f32x4 x3 = *(const f32x4*)&fl[32768 + lr * 16 + 12];
            float* orow = out + (size_t)grow * OUT_DIM;
#pragma unroll
            for (int n = 0; n < 4; n++) {
                int lc = wnBase + n * 16 + frow;
                int s = (lc >> 1) & 3;
                int bi = (a * 256 + lc) * 16;
                f32x4 b0 = *(const f32x4*)&fl[bi + ((0 ^ s) << 2)];
                f32x4 b1 = *(const f32x4*)&fl[bi + ((1 ^ s) << 2)];
                f32x4 b2 = *(const f32x4*)&fl[bi + ((2 ^ s) << 2)];
                f32x4 b3 = *(const f32x4*)&fl[bi + ((3 ^ s) << 2)];
                float l = x0[0]*b0[0] + x0[1]*b0[1] + x0[2]*b0[2] + x0[3]*b0[3]
                        + x1[0]*b1[0] + x1[1]*b1[1] + x1[2]*b1[2] + x1[3]*b1[3]
                        + x2[0]*b2[0] + x2[1]*b2[1] + x2[2]*b2[2] + x2[3]*b2[3]
                        + x3[0]*b3[0] + x3[1]*b3[1] + x3[2]*b3[2] + x3[3]*b3[3];
                orow[colBase + lc] = acc[m][n][rg] + biasv[n] + SCALING * l;
            }
        }
    }
}

extern "C" void kernel_launch(void* const* d_in, const int* in_sizes, int n_in,
                              void* d_out, int out_size, void* d_ws, size_t ws_size,
                              hipStream_t stream) {
    const float* x = (const float*)d_in[0];
    const float* W = (const float*)d_in[1];
    const float* bias = (const float*)d_in[2];
    const float* Abuf = (const float*)d_in[3];
    const float* Bbuf = (const float*)d_in[4];   // [1, A, OUT, R]
    const int* widx = (const int*)d_in[5];
    float* out = (float*)d_out;

    size_t xbf_elems = (size_t)S_DIM * IN_DIM;
    size_t wbf_elems = (size_t)OUT_DIM * IN_DIM;
    size_t abf_elems = (size_t)8 * 16 * IN_DIM;
    size_t need = xbf_elems * 2 + wbf_elems * 2 + (size_t)S_DIM * 16 * 4 + abf_elems * 2;
    if (ws_size < need) return;

    unsigned short* xbf = (unsigned short*)d_ws;
    unsigned short* wbf = xbf + xbf_elems;
    float* xa_sel = (float*)(wbf + wbf_elems);
    unsigned short* abf = (unsigned short*)(xa_sel + (size_t)S_DIM * 16);

    hipFuncSetAttribute(reinterpret_cast<const void*>(gemm256),
                        hipFuncAttributeMaxDynamicSharedMemorySize, 147456);

    convert_w<<<2048, 256, 0, stream>>>(W, wbf, (int)(wbf_elems / 4));
    convert_w<<<512, 256, 0, stream>>>(Abuf, abf, (int)(abf_elems / 4));
    xak<<<256, 512, 0, stream>>>(x, abf, widx, xbf, xa_sel);
    gemm256<<<512, 512, 147456, stream>>>(xbf, wbf, bias, xa_sel, Bbuf, widx, out);
}